// Round 1
// 1542.991 us; speedup vs baseline: 1.8048x; 1.8048x over previous
//
#include <hip/hip_runtime.h>
#include <hip/hip_bf16.h>
#include <math.h>

#define LOG2E 1.44269504088896340736f

typedef __bf16 bf16x8 __attribute__((ext_vector_type(8)));
typedef float floatx4 __attribute__((ext_vector_type(4)));

static constexpr int VOCAB = 32000, D_MODEL = 1024, D_STATE = 16;
static constexpr int D_INNER = 2048, DT_RANK = 64, NB = 2, LSEQ = 2048;
static constexpr int NTOK = NB * LSEQ;  // 4096
static constexpr int CL = 64, NCHUNK = LSEQ / CL;  // 32 chunks of 64 steps

__device__ __forceinline__ unsigned short f2bf(float f) {
    union { __hip_bfloat16 h; unsigned short u; } v;
    v.h = __float2bfloat16(f);
    return v.u;
}

// ---------------- embedding gather -> bf16 ----------------
__global__ void embed_kernel(const int* __restrict__ tok, const float* __restrict__ emb,
                             unsigned short* __restrict__ ubf) {
    int g = blockIdx.x * blockDim.x + threadIdx.x;   // NTOK * D_MODEL/4
    int row = g >> 8;                                 // 256 float4 per row
    int c4 = (g & 255) * 4;
    if (row >= NTOK) return;
    int t = tok[row];
    float4 v = *(const float4*)(emb + (size_t)t * D_MODEL + c4);
    ushort4 o;
    o.x = f2bf(v.x); o.y = f2bf(v.y); o.z = f2bf(v.z); o.w = f2bf(v.w);
    *(ushort4*)(ubf + (size_t)row * D_MODEL + c4) = o;
}

// ---------------- generic f32 -> bf16 convert ----------------
__global__ void cvt_kernel(const float* __restrict__ in, unsigned short* __restrict__ out, int n4) {
    int g = blockIdx.x * blockDim.x + threadIdx.x;
    if (g >= n4) return;
    float4 v = ((const float4*)in)[g];
    ushort4 o;
    o.x = f2bf(v.x); o.y = f2bf(v.y); o.z = f2bf(v.z); o.w = f2bf(v.w);
    ((ushort4*)out)[g] = o;
}

// ---------------- causal depthwise conv (K=4) + silu, writes f32 + bf16 ----------------
__global__ void conv_silu_kernel(const float* __restrict__ xz, const float* __restrict__ cw,
                                 const float* __restrict__ cb, float* __restrict__ xf,
                                 unsigned short* __restrict__ xbf) {
    int g = blockIdx.x * blockDim.x + threadIdx.x;   // NTOK * D_INNER
    if (g >= NTOK * D_INNER) return;
    int d = g & (D_INNER - 1);
    int row = g >> 11;
    int l = row & (LSEQ - 1);
    float w0 = cw[d * 4 + 0], w1 = cw[d * 4 + 1], w2 = cw[d * 4 + 2], w3 = cw[d * 4 + 3];
    const float* xin = xz + (size_t)row * (2 * D_INNER) + d;
    const ptrdiff_t S = 2 * D_INNER;
    float acc = cb[d] + xin[0] * w3;
    if (l >= 1) acc += xin[-S] * w2;
    if (l >= 2) acc += xin[-2 * S] * w1;
    if (l >= 3) acc += xin[-3 * S] * w0;
    float sig = 1.f / (1.f + __builtin_amdgcn_exp2f(-acc * LOG2E));
    float v = acc * sig;
    xf[g] = v;
    xbf[g] = f2bf(v);
}

// ---------------- extract dt columns (stride 96 -> dense 64) as bf16 ----------------
__global__ void dtin_kernel(const float* __restrict__ xdbl, unsigned short* __restrict__ dtin) {
    int g = blockIdx.x * blockDim.x + threadIdx.x;   // NTOK * 64
    if (g >= NTOK * DT_RANK) return;
    int row = g >> 6, r = g & 63;
    dtin[g] = f2bf(xdbl[(size_t)row * 96 + r]);
}

// ---------------- As = -exp(A_log) * log2(e) ----------------
__global__ void As_kernel(const float* __restrict__ A_log, float* __restrict__ As, int n) {
    int g = blockIdx.x * blockDim.x + threadIdx.x;
    if (g >= n) return;
    As[g] = -__builtin_amdgcn_exp2f(A_log[g] * LOG2E) * LOG2E;
}

// ================= chunked parallel selective scan =================
// Recurrence h_l = dA_l * h_{l-1} + dt_l*B_l*x_l is linear, so per chunk:
//   h_end = (prod dA) * h_in + h_part.
// part1: per (b,d,s,chunk) compute P = exp2(sum dt*a2) and h_part (h_in = 0).
// combine: per (b,d,s) serial scan over NCHUNK chunk states -> h_init per chunk.
// part2: rerun chunk from h_init, fused epilogue (y = (h.C + D*x)*silu(z), bf16).
// Thread index bits: s:4 | d:11 | c:5 | b:1  (2,097,152 threads for part1/2)

__global__ void scan_part1(const float* __restrict__ dt, const float* __restrict__ x,
                           const float* __restrict__ xdbl, const float* __restrict__ As,
                           float* __restrict__ Pc, float* __restrict__ Hc) {
    int g = blockIdx.x * blockDim.x + threadIdx.x;   // NB*NCHUNK*D_INNER*16
    int s = g & 15;
    int d = (g >> 4) & (D_INNER - 1);
    int c = (g >> 15) & (NCHUNK - 1);
    int b = g >> 20;
    float a2 = As[d * 16 + s];
    int row0 = b * LSEQ + c * CL;
    const float* dtp = dt + (size_t)row0 * D_INNER + d;
    const float* xp = x + (size_t)row0 * D_INNER + d;
    const float* bp = xdbl + (size_t)row0 * 96 + 64 + s;
    float h = 0.f, esum = 0.f;
    for (int l = 0; l < CL; ++l) {
        float dtv = dtp[(size_t)l * D_INNER];
        float xv = xp[(size_t)l * D_INNER];
        float Bv = bp[(size_t)l * 96];
        float e = dtv * a2;          // <= 0 (dt >= 0, a2 < 0), so exp2 <= 1: no overflow
        esum += e;
        float dA = __builtin_amdgcn_exp2f(e);
        h = dA * h + dtv * Bv * xv;
    }
    Pc[g] = __builtin_amdgcn_exp2f(esum);
    Hc[g] = h;
}

__global__ void scan_combine(const float* __restrict__ Pc, const float* __restrict__ Hc,
                             float* __restrict__ Hinit) {
    int g = blockIdx.x * blockDim.x + threadIdx.x;   // NB*D_INNER*16 = 65536
    int ds = g & (D_INNER * D_STATE - 1);
    int b = g >> 15;
    size_t base = (size_t)b * NCHUNK * D_INNER * D_STATE + ds;
    float h = 0.f;
    for (int c = 0; c < NCHUNK; ++c) {
        size_t idx = base + (size_t)c * (D_INNER * D_STATE);
        Hinit[idx] = h;                 // exclusive scan: state entering chunk c
        h = Pc[idx] * h + Hc[idx];
    }
}

__global__ void scan_part2(const float* __restrict__ dt, const float* __restrict__ x,
                           const float* __restrict__ xdbl, const float* __restrict__ xz,
                           const float* __restrict__ As, const float* __restrict__ Dvec,
                           const float* __restrict__ Hinit, unsigned short* __restrict__ ybf) {
    int g = blockIdx.x * blockDim.x + threadIdx.x;   // NB*NCHUNK*D_INNER*16
    int s = g & 15;
    int d = (g >> 4) & (D_INNER - 1);
    int c = (g >> 15) & (NCHUNK - 1);
    int b = g >> 20;
    float a2 = As[d * 16 + s];
    float Dv = Dvec[d];
    int row0 = b * LSEQ + c * CL;
    const float* dtp = dt + (size_t)row0 * D_INNER + d;
    const float* xp = x + (size_t)row0 * D_INNER + d;
    const float* bp = xdbl + (size_t)row0 * 96 + 64 + s;
    const float* cp = xdbl + (size_t)row0 * 96 + 80 + s;
    const float* zp = xz + (size_t)row0 * 2 * D_INNER + D_INNER + d;
    unsigned short* yp = ybf + (size_t)row0 * D_INNER + d;
    float h = Hinit[g];
    for (int l = 0; l < CL; ++l) {
        float dtv = dtp[(size_t)l * D_INNER];
        float xv = xp[(size_t)l * D_INNER];
        float Bv = bp[(size_t)l * 96];
        float Cv = cp[(size_t)l * 96];
        float dA = __builtin_amdgcn_exp2f(dtv * a2);
        h = dA * h + dtv * Bv * xv;
        float p = h * Cv;
        p += __shfl_xor(p, 1);
        p += __shfl_xor(p, 2);
        p += __shfl_xor(p, 4);
        p += __shfl_xor(p, 8);
        if (s == 0) {
            float zv = zp[(size_t)l * 2 * D_INNER];
            float sig = 1.f / (1.f + __builtin_amdgcn_exp2f(-zv * LOG2E));
            float y = (p + Dv * xv) * (zv * sig);
            yp[(size_t)l * D_INNER] = f2bf(y);
        }
    }
}

// ---------------- bf16 MFMA GEMM: C[M,N] = A[M,K] * Bw[N,K]^T (both row-major, K contiguous)
// epi: 0 = fp32 store; 1 = fp32 bias+softplus; 2 = fp32 bias; 3 = bf16 store
__global__ __launch_bounds__(256, 2)
void gemm_bf16(const unsigned short* __restrict__ A, const unsigned short* __restrict__ Bw,
               float* __restrict__ Cf, unsigned short* __restrict__ Cb,
               const float* __restrict__ bias, int M, int N, int K, int epi) {
    constexpr int BM = 128, BN = 128, BK = 32, LDT = 40;  // 40*2B=80B stride: 2-way bank alias (free)
    __shared__ __align__(16) unsigned short lA[BM * LDT];
    __shared__ __align__(16) unsigned short lB[BN * LDT];
    int tid = threadIdx.x;
    int wave = tid >> 6, lane = tid & 63;
    int quad = lane >> 4, l16 = lane & 15;
    int wr = wave >> 1, wc = wave & 1;
    int m0 = blockIdx.y * BM, n0 = blockIdx.x * BN;

    floatx4 acc[4][4] = {};

    int r0 = tid >> 2, ch = tid & 3;  // 64 rows per pass, 4x 8-elem chunks per row
    int bn0 = n0 + r0; if (bn0 >= N) bn0 = N - 1;
    int bn1 = n0 + r0 + 64; if (bn1 >= N) bn1 = N - 1;
    const int nK = K / BK;
    for (int kt = 0; kt < nK; ++kt) {
        int k0 = kt * BK + ch * 8;
        uint4 va0 = *(const uint4*)(A + (size_t)(m0 + r0) * K + k0);
        uint4 va1 = *(const uint4*)(A + (size_t)(m0 + r0 + 64) * K + k0);
        uint4 vb0 = *(const uint4*)(Bw + (size_t)bn0 * K + k0);
        uint4 vb1 = *(const uint4*)(Bw + (size_t)bn1 * K + k0);
        __syncthreads();
        *(uint4*)&lA[r0 * LDT + ch * 8] = va0;
        *(uint4*)&lA[(r0 + 64) * LDT + ch * 8] = va1;
        *(uint4*)&lB[r0 * LDT + ch * 8] = vb0;
        *(uint4*)&lB[(r0 + 64) * LDT + ch * 8] = vb1;
        __syncthreads();
        bf16x8 af[4], bfr[4];
#pragma unroll
        for (int t = 0; t < 4; ++t) {
            af[t] = *(const bf16x8*)&lA[(wr * 64 + t * 16 + l16) * LDT + quad * 8];
            bfr[t] = *(const bf16x8*)&lB[(wc * 64 + t * 16 + l16) * LDT + quad * 8];
        }
#pragma unroll
        for (int mt = 0; mt < 4; ++mt)
#pragma unroll
            for (int nt = 0; nt < 4; ++nt)
                acc[mt][nt] = __builtin_amdgcn_mfma_f32_16x16x32_bf16(af[mt], bfr[nt], acc[mt][nt], 0, 0, 0);
    }
#pragma unroll
    for (int mt = 0; mt < 4; ++mt) {
#pragma unroll
        for (int nt = 0; nt < 4; ++nt) {
            int col = n0 + wc * 64 + nt * 16 + l16;
            if (col >= N) continue;
            float bv = (epi == 1 || epi == 2) ? bias[col] : 0.f;
#pragma unroll
            for (int r = 0; r < 4; ++r) {
                int row = m0 + wr * 64 + mt * 16 + quad * 4 + r;
                float v = acc[mt][nt][r] + bv;
                if (epi == 1) v = (v > 20.f) ? v : log1pf(__builtin_amdgcn_exp2f(v * LOG2E));
                if (epi == 3) Cb[(size_t)row * N + col] = f2bf(v);
                else Cf[(size_t)row * N + col] = v;
            }
        }
    }
}

extern "C" void kernel_launch(void* const* d_in, const int* in_sizes, int n_in,
                              void* d_out, int out_size, void* d_ws, size_t ws_size,
                              hipStream_t stream) {
    (void)in_sizes; (void)n_in; (void)out_size; (void)ws_size;
    const int* tokens = (const int*)d_in[0];
    const float* emb = (const float*)d_in[1];
    const float* in_proj_w = (const float*)d_in[2];
    const float* conv_w = (const float*)d_in[3];
    const float* conv_b = (const float*)d_in[4];
    const float* x_proj_w = (const float*)d_in[5];
    const float* dt_proj_w = (const float*)d_in[6];
    const float* dt_proj_b = (const float*)d_in[7];
    const float* A_log = (const float*)d_in[8];
    const float* Dvec = (const float*)d_in[9];
    const float* out_proj_w = (const float*)d_in[10];
    const float* head_w = (const float*)d_in[11];
    const float* head_b = (const float*)d_in[12];
    float* logits = (float*)d_out;

    char* ws = (char*)d_ws;
    size_t off = 0;
    auto alloc = [&](size_t bytes) -> void* {
        void* p = ws + off;
        off = (off + bytes + 255) & ~(size_t)255;
        return p;
    };
    unsigned short* u_bf = (unsigned short*)alloc((size_t)NTOK * D_MODEL * 2);
    unsigned short* Win_bf = (unsigned short*)alloc((size_t)2 * D_INNER * D_MODEL * 2);
    float* xz = (float*)alloc((size_t)NTOK * 2 * D_INNER * 4);           // 67 MB
    float* xf = (float*)alloc((size_t)NTOK * D_INNER * 4);
    unsigned short* x_bf = (unsigned short*)alloc((size_t)NTOK * D_INNER * 2);
    unsigned short* Wxp_bf = (unsigned short*)alloc((size_t)96 * D_INNER * 2);
    float* xdbl = (float*)alloc((size_t)NTOK * 96 * 4);
    unsigned short* dtin_bf = (unsigned short*)alloc((size_t)NTOK * DT_RANK * 2);
    unsigned short* Wdt_bf = (unsigned short*)alloc((size_t)D_INNER * DT_RANK * 2);
    float* dtf = (float*)alloc((size_t)NTOK * D_INNER * 4);
    float* As = (float*)alloc((size_t)D_INNER * D_STATE * 4);
    unsigned short* y_bf = (unsigned short*)alloc((size_t)NTOK * D_INNER * 2);
    unsigned short* Wout_bf = (unsigned short*)alloc((size_t)D_MODEL * D_INNER * 2);
    unsigned short* out_bf = (unsigned short*)alloc((size_t)NTOK * D_MODEL * 2);
    float* Hinit = (float*)alloc((size_t)NB * NCHUNK * D_INNER * D_STATE * 4);  // 8.4 MB
    // head_w bf16 (65.5 MB) aliases xz (67 MB) — xz is dead after the scan
    unsigned short* Whead_bf = (unsigned short*)xz;
    // chunk-state buffers alias u_bf / Win_bf (each exactly 8,388,608 B, dead after GEMM #3)
    float* Pc = (float*)u_bf;       // NB*NCHUNK*D_INNER*D_STATE * 4 = 8,388,608 B
    float* Hc = (float*)Win_bf;     // same size

    dim3 blk(256);

    // 1. embedding gather
    embed_kernel<<<dim3(NTOK * D_MODEL / 4 / 256), blk, 0, stream>>>(tokens, emb, u_bf);
    // 2. in_proj weight -> bf16
    cvt_kernel<<<dim3(2 * D_INNER * D_MODEL / 4 / 256), blk, 0, stream>>>(in_proj_w, Win_bf, 2 * D_INNER * D_MODEL / 4);
    // 3. xz = u @ in_proj_w^T   [4096 x 4096], K=1024
    gemm_bf16<<<dim3(2 * D_INNER / 128, NTOK / 128), blk, 0, stream>>>(
        u_bf, Win_bf, xz, nullptr, nullptr, NTOK, 2 * D_INNER, D_MODEL, 0);
    // 4. conv + silu
    conv_silu_kernel<<<dim3(NTOK * D_INNER / 256), blk, 0, stream>>>(xz, conv_w, conv_b, xf, x_bf);
    // 5. x_proj weight -> bf16
    cvt_kernel<<<dim3((96 * D_INNER / 4 + 255) / 256), blk, 0, stream>>>(x_proj_w, Wxp_bf, 96 * D_INNER / 4);
    // 6. x_dbl = x @ x_proj_w^T  [4096 x 96], K=2048
    gemm_bf16<<<dim3(1, NTOK / 128), blk, 0, stream>>>(
        x_bf, Wxp_bf, xdbl, nullptr, nullptr, NTOK, 96, D_INNER, 0);
    // 7. extract dt-rank columns -> bf16
    dtin_kernel<<<dim3(NTOK * DT_RANK / 256), blk, 0, stream>>>(xdbl, dtin_bf);
    // 8. dt_proj weight -> bf16
    cvt_kernel<<<dim3((D_INNER * DT_RANK / 4 + 255) / 256), blk, 0, stream>>>(dt_proj_w, Wdt_bf, D_INNER * DT_RANK / 4);
    // 9. dt = softplus(dtin @ dt_proj_w^T + b)  [4096 x 2048], K=64
    gemm_bf16<<<dim3(D_INNER / 128, NTOK / 128), blk, 0, stream>>>(
        dtin_bf, Wdt_bf, dtf, nullptr, dt_proj_b, NTOK, D_INNER, DT_RANK, 1);
    // 10. As
    As_kernel<<<dim3((D_INNER * D_STATE + 255) / 256), blk, 0, stream>>>(A_log, As, D_INNER * D_STATE);
    // 11. chunked selective scan (3 kernels; fused +D*x, *silu(z), bf16 out)
    scan_part1<<<dim3(NB * NCHUNK * D_INNER * D_STATE / 256), blk, 0, stream>>>(
        dtf, xf, xdbl, As, Pc, Hc);
    scan_combine<<<dim3(NB * D_INNER * D_STATE / 256), blk, 0, stream>>>(Pc, Hc, Hinit);
    scan_part2<<<dim3(NB * NCHUNK * D_INNER * D_STATE / 256), blk, 0, stream>>>(
        dtf, xf, xdbl, xz, As, Dvec, Hinit, y_bf);
    // 12. out_proj weight -> bf16
    cvt_kernel<<<dim3(D_MODEL * D_INNER / 4 / 256), blk, 0, stream>>>(out_proj_w, Wout_bf, D_MODEL * D_INNER / 4);
    // 13. out = y @ out_proj_w^T  [4096 x 1024], K=2048, bf16 out
    gemm_bf16<<<dim3(D_MODEL / 128, NTOK / 128), blk, 0, stream>>>(
        y_bf, Wout_bf, nullptr, out_bf, nullptr, NTOK, D_MODEL, D_INNER, 3);
    // 14. head weight -> bf16 (into dead xz buffer)
    cvt_kernel<<<dim3(VOCAB * D_MODEL / 4 / 256), blk, 0, stream>>>(head_w, Whead_bf, VOCAB * D_MODEL / 4);
    // 15. logits = out @ head_w^T + head_b  [4096 x 32000], K=1024
    gemm_bf16<<<dim3(VOCAB / 128, NTOK / 128), blk, 0, stream>>>(
        out_bf, Whead_bf, logits, nullptr, head_b, NTOK, VOCAB, D_MODEL, 2);
}

// Round 2
// 1507.239 us; speedup vs baseline: 1.8476x; 1.0237x over previous
//
#include <hip/hip_runtime.h>
#include <hip/hip_bf16.h>
#include <math.h>

#define LOG2E 1.44269504088896340736f

typedef __bf16 bf16x8 __attribute__((ext_vector_type(8)));
typedef float floatx4 __attribute__((ext_vector_type(4)));

static constexpr int VOCAB = 32000, D_MODEL = 1024, D_STATE = 16;
static constexpr int D_INNER = 2048, DT_RANK = 64, NB = 2, LSEQ = 2048;
static constexpr int NTOK = NB * LSEQ;  // 4096
static constexpr int CL = 64, NCHUNK = LSEQ / CL;  // 32 chunks of 64 steps

__device__ __forceinline__ unsigned short f2bf(float f) {
    union { __hip_bfloat16 h; unsigned short u; } v;
    v.h = __float2bfloat16(f);
    return v.u;
}

// ---------------- embedding gather -> bf16 ----------------
__global__ void embed_kernel(const int* __restrict__ tok, const float* __restrict__ emb,
                             unsigned short* __restrict__ ubf) {
    int g = blockIdx.x * blockDim.x + threadIdx.x;   // NTOK * D_MODEL/4
    int row = g >> 8;                                 // 256 float4 per row
    int c4 = (g & 255) * 4;
    if (row >= NTOK) return;
    int t = tok[row];
    float4 v = *(const float4*)(emb + (size_t)t * D_MODEL + c4);
    ushort4 o;
    o.x = f2bf(v.x); o.y = f2bf(v.y); o.z = f2bf(v.z); o.w = f2bf(v.w);
    *(ushort4*)(ubf + (size_t)row * D_MODEL + c4) = o;
}

// ---------------- generic f32 -> bf16 convert ----------------
__global__ void cvt_kernel(const float* __restrict__ in, unsigned short* __restrict__ out, int n4) {
    int g = blockIdx.x * blockDim.x + threadIdx.x;
    if (g >= n4) return;
    float4 v = ((const float4*)in)[g];
    ushort4 o;
    o.x = f2bf(v.x); o.y = f2bf(v.y); o.z = f2bf(v.z); o.w = f2bf(v.w);
    ((ushort4*)out)[g] = o;
}

// ---------------- causal depthwise conv (K=4) + silu, writes f32 + bf16 ----------------
__global__ void conv_silu_kernel(const float* __restrict__ xz, const float* __restrict__ cw,
                                 const float* __restrict__ cb, float* __restrict__ xf,
                                 unsigned short* __restrict__ xbf) {
    int g = blockIdx.x * blockDim.x + threadIdx.x;   // NTOK * D_INNER
    if (g >= NTOK * D_INNER) return;
    int d = g & (D_INNER - 1);
    int row = g >> 11;
    int l = row & (LSEQ - 1);
    float w0 = cw[d * 4 + 0], w1 = cw[d * 4 + 1], w2 = cw[d * 4 + 2], w3 = cw[d * 4 + 3];
    const float* xin = xz + (size_t)row * (2 * D_INNER) + d;
    const ptrdiff_t S = 2 * D_INNER;
    float acc = cb[d] + xin[0] * w3;
    if (l >= 1) acc += xin[-S] * w2;
    if (l >= 2) acc += xin[-2 * S] * w1;
    if (l >= 3) acc += xin[-3 * S] * w0;
    float sig = 1.f / (1.f + __builtin_amdgcn_exp2f(-acc * LOG2E));
    float v = acc * sig;
    xf[g] = v;
    xbf[g] = f2bf(v);
}

// ---------------- extract dt columns (stride 96 -> dense 64) as bf16 ----------------
__global__ void dtin_kernel(const float* __restrict__ xdbl, unsigned short* __restrict__ dtin) {
    int g = blockIdx.x * blockDim.x + threadIdx.x;   // NTOK * 64
    if (g >= NTOK * DT_RANK) return;
    int row = g >> 6, r = g & 63;
    dtin[g] = f2bf(xdbl[(size_t)row * 96 + r]);
}

// ---------------- As = -exp(A_log) * log2(e) ----------------
__global__ void As_kernel(const float* __restrict__ A_log, float* __restrict__ As, int n) {
    int g = blockIdx.x * blockDim.x + threadIdx.x;
    if (g >= n) return;
    As[g] = -__builtin_amdgcn_exp2f(A_log[g] * LOG2E) * LOG2E;
}

// ================= chunked parallel selective scan =================
// h_l = dA_l * h_{l-1} + dt_l*B_l*x_l is linear; per chunk: h_end = (prod dA)*h_in + h_part.
// part1: per (b,d,s,chunk) P = exp2(sum dt*a2), h_part (h_in = 0).
// combine: per (b,d,s) serial scan over NCHUNK chunk states -> h_init per chunk.
// part2: rerun chunk from h_init, fused epilogue.
// Thread index bits: s:4 | d:11 | c:5 | b:1

__global__ void scan_part1(const float* __restrict__ dt, const float* __restrict__ x,
                           const float* __restrict__ xdbl, const float* __restrict__ As,
                           float* __restrict__ Pc, float* __restrict__ Hc) {
    int g = blockIdx.x * blockDim.x + threadIdx.x;   // NB*NCHUNK*D_INNER*16
    int s = g & 15;
    int d = (g >> 4) & (D_INNER - 1);
    int c = (g >> 15) & (NCHUNK - 1);
    int b = g >> 20;
    float a2 = As[d * 16 + s];
    int row0 = b * LSEQ + c * CL;
    const float* dtp = dt + (size_t)row0 * D_INNER + d;
    const float* xp = x + (size_t)row0 * D_INNER + d;
    const float* bp = xdbl + (size_t)row0 * 96 + 64 + s;
    float h = 0.f, esum = 0.f;
    for (int l = 0; l < CL; ++l) {
        float dtv = dtp[(size_t)l * D_INNER];
        float xv = xp[(size_t)l * D_INNER];
        float Bv = bp[(size_t)l * 96];
        float e = dtv * a2;          // <= 0, exp2 <= 1: no overflow
        esum += e;
        float dA = __builtin_amdgcn_exp2f(e);
        h = dA * h + dtv * Bv * xv;
    }
    Pc[g] = __builtin_amdgcn_exp2f(esum);
    Hc[g] = h;
}

__global__ void scan_combine(const float* __restrict__ Pc, const float* __restrict__ Hc,
                             float* __restrict__ Hinit) {
    int g = blockIdx.x * blockDim.x + threadIdx.x;   // NB*D_INNER*16 = 65536
    int ds = g & (D_INNER * D_STATE - 1);
    int b = g >> 15;
    size_t base = (size_t)b * NCHUNK * D_INNER * D_STATE + ds;
    float h = 0.f;
    for (int c = 0; c < NCHUNK; ++c) {
        size_t idx = base + (size_t)c * (D_INNER * D_STATE);
        Hinit[idx] = h;                 // exclusive scan: state entering chunk c
        h = Pc[idx] * h + Hc[idx];
    }
}

__global__ void scan_part2(const float* __restrict__ dt, const float* __restrict__ x,
                           const float* __restrict__ xdbl, const float* __restrict__ xz,
                           const float* __restrict__ As, const float* __restrict__ Dvec,
                           const float* __restrict__ Hinit, unsigned short* __restrict__ ybf) {
    int g = blockIdx.x * blockDim.x + threadIdx.x;   // NB*NCHUNK*D_INNER*16
    int s = g & 15;
    int d = (g >> 4) & (D_INNER - 1);
    int c = (g >> 15) & (NCHUNK - 1);
    int b = g >> 20;
    float a2 = As[d * 16 + s];
    float Dv = Dvec[d];
    int row0 = b * LSEQ + c * CL;
    const float* dtp = dt + (size_t)row0 * D_INNER + d;
    const float* xp = x + (size_t)row0 * D_INNER + d;
    const float* bp = xdbl + (size_t)row0 * 96 + 64 + s;
    const float* cp = xdbl + (size_t)row0 * 96 + 80 + s;
    const float* zp = xz + (size_t)row0 * 2 * D_INNER + D_INNER + d;
    unsigned short* yp = ybf + (size_t)row0 * D_INNER + d;
    float h = Hinit[g];
    for (int l = 0; l < CL; ++l) {
        float dtv = dtp[(size_t)l * D_INNER];
        float xv = xp[(size_t)l * D_INNER];
        float Bv = bp[(size_t)l * 96];
        float Cv = cp[(size_t)l * 96];
        float dA = __builtin_amdgcn_exp2f(dtv * a2);
        h = dA * h + dtv * Bv * xv;
        float p = h * Cv;
        p += __shfl_xor(p, 1);
        p += __shfl_xor(p, 2);
        p += __shfl_xor(p, 4);
        p += __shfl_xor(p, 8);
        if (s == 0) {
            float zv = zp[(size_t)l * 2 * D_INNER];
            float sig = 1.f / (1.f + __builtin_amdgcn_exp2f(-zv * LOG2E));
            float y = (p + Dv * xv) * (zv * sig);
            yp[(size_t)l * D_INNER] = f2bf(y);
        }
    }
}

// ---------------- bf16 MFMA GEMM: C[M,N] = A[M,K] * Bw[N,K]^T (both row-major, K contiguous)
// m97 structure: global_load_lds width=16 into LINEAR [128][32] LDS tiles (no pad —
// gload_lds writes wave-base + lane*16, pad would break it). Group-M block swizzle
// for B-panel L2/L3 reuse. epi: 0 = fp32; 1 = fp32 bias+softplus; 2 = fp32 bias; 3 = bf16
__global__ __launch_bounds__(256, 2)
void gemm_bf16(const unsigned short* __restrict__ A, const unsigned short* __restrict__ Bw,
               float* __restrict__ Cf, unsigned short* __restrict__ Cb,
               const float* __restrict__ bias, int M, int N, int K, int epi) {
    constexpr int BM = 128, BN = 128, BK = 32;
    __shared__ __align__(16) unsigned short lA[BM * BK];  // 8 KB
    __shared__ __align__(16) unsigned short lB[BN * BK];  // 8 KB
    int tid = threadIdx.x;
    int wave = tid >> 6, lane = tid & 63;
    int quad = lane >> 4, l16 = lane & 15;
    int wr = wave >> 1, wc = wave & 1;

    // group-M swizzle: 8 consecutive blocks share one B-panel (cuts B re-fetch 8x)
    int num_n = gridDim.x, num_m = gridDim.y;
    int lin = blockIdx.y * num_n + blockIdx.x;
    constexpr int GROUP_M = 8;
    int gsize = GROUP_M * num_n;
    int gid = lin / gsize;
    int fm = gid * GROUP_M;
    int gsz = (num_m - fm < GROUP_M) ? (num_m - fm) : GROUP_M;
    int rem = lin - gid * gsize;
    int m0 = (fm + rem % gsz) * BM;
    int n0 = (rem / gsz) * BN;

    floatx4 acc[4][4] = {};

    // staging: wave w fills 1 KB chunks {w, w+4} of each 8 KB tile.
    // chunk c covers rows [c*16, c*16+16): lane l -> row c*16 + l/4, col (l&3)*8 shorts.
    int crow = lane >> 2;
    int ccol = (lane & 3) * 8;
    int rA0 = m0 + wave * 16 + crow;
    int rA1 = rA0 + 64;
    int rB0 = n0 + wave * 16 + crow; if (rB0 >= N) rB0 = N - 1;
    int rB1 = n0 + 64 + wave * 16 + crow; if (rB1 >= N) rB1 = N - 1;
    const unsigned short* pA0 = A + (size_t)rA0 * K + ccol;
    const unsigned short* pA1 = A + (size_t)rA1 * K + ccol;
    const unsigned short* pB0 = Bw + (size_t)rB0 * K + ccol;
    const unsigned short* pB1 = Bw + (size_t)rB1 * K + ccol;
    typedef const __attribute__((address_space(1))) unsigned int gu32;
    typedef __attribute__((address_space(3))) unsigned int lu32;
    lu32* dA0 = (lu32*)(lA + wave * 512);
    lu32* dA1 = (lu32*)(lA + (wave + 4) * 512);
    lu32* dB0 = (lu32*)(lB + wave * 512);
    lu32* dB1 = (lu32*)(lB + (wave + 4) * 512);

    const int nK = K / BK;
    for (int kt = 0; kt < nK; ++kt) {
        __syncthreads();   // previous tile's ds_reads complete before overwrite
        __builtin_amdgcn_global_load_lds((gu32*)(pA0 + kt * BK), dA0, 16, 0, 0);
        __builtin_amdgcn_global_load_lds((gu32*)(pA1 + kt * BK), dA1, 16, 0, 0);
        __builtin_amdgcn_global_load_lds((gu32*)(pB0 + kt * BK), dB0, 16, 0, 0);
        __builtin_amdgcn_global_load_lds((gu32*)(pB1 + kt * BK), dB1, 16, 0, 0);
        __syncthreads();   // drains vmcnt before barrier (compiler-inserted)
        bf16x8 af[4], bfr[4];
#pragma unroll
        for (int t = 0; t < 4; ++t) {
            af[t] = *(const bf16x8*)&lA[(wr * 64 + t * 16 + l16) * BK + quad * 8];
            bfr[t] = *(const bf16x8*)&lB[(wc * 64 + t * 16 + l16) * BK + quad * 8];
        }
#pragma unroll
        for (int mt = 0; mt < 4; ++mt)
#pragma unroll
            for (int nt = 0; nt < 4; ++nt)
                acc[mt][nt] = __builtin_amdgcn_mfma_f32_16x16x32_bf16(af[mt], bfr[nt], acc[mt][nt], 0, 0, 0);
    }
#pragma unroll
    for (int mt = 0; mt < 4; ++mt) {
#pragma unroll
        for (int nt = 0; nt < 4; ++nt) {
            int col = n0 + wc * 64 + nt * 16 + l16;
            if (col >= N) continue;
            float bv = (epi == 1 || epi == 2) ? bias[col] : 0.f;
#pragma unroll
            for (int r = 0; r < 4; ++r) {
                int row = m0 + wr * 64 + mt * 16 + quad * 4 + r;
                float v = acc[mt][nt][r] + bv;
                if (epi == 1) v = (v > 20.f) ? v : log1pf(__builtin_amdgcn_exp2f(v * LOG2E));
                if (epi == 3) Cb[(size_t)row * N + col] = f2bf(v);
                else Cf[(size_t)row * N + col] = v;
            }
        }
    }
}

extern "C" void kernel_launch(void* const* d_in, const int* in_sizes, int n_in,
                              void* d_out, int out_size, void* d_ws, size_t ws_size,
                              hipStream_t stream) {
    (void)in_sizes; (void)n_in; (void)out_size; (void)ws_size;
    const int* tokens = (const int*)d_in[0];
    const float* emb = (const float*)d_in[1];
    const float* in_proj_w = (const float*)d_in[2];
    const float* conv_w = (const float*)d_in[3];
    const float* conv_b = (const float*)d_in[4];
    const float* x_proj_w = (const float*)d_in[5];
    const float* dt_proj_w = (const float*)d_in[6];
    const float* dt_proj_b = (const float*)d_in[7];
    const float* A_log = (const float*)d_in[8];
    const float* Dvec = (const float*)d_in[9];
    const float* out_proj_w = (const float*)d_in[10];
    const float* head_w = (const float*)d_in[11];
    const float* head_b = (const float*)d_in[12];
    float* logits = (float*)d_out;

    char* ws = (char*)d_ws;
    size_t off = 0;
    auto alloc = [&](size_t bytes) -> void* {
        void* p = ws + off;
        off = (off + bytes + 255) & ~(size_t)255;
        return p;
    };
    unsigned short* u_bf = (unsigned short*)alloc((size_t)NTOK * D_MODEL * 2);
    unsigned short* Win_bf = (unsigned short*)alloc((size_t)2 * D_INNER * D_MODEL * 2);
    float* xz = (float*)alloc((size_t)NTOK * 2 * D_INNER * 4);           // 67 MB
    float* xf = (float*)alloc((size_t)NTOK * D_INNER * 4);
    unsigned short* x_bf = (unsigned short*)alloc((size_t)NTOK * D_INNER * 2);
    unsigned short* Wxp_bf = (unsigned short*)alloc((size_t)96 * D_INNER * 2);
    float* xdbl = (float*)alloc((size_t)NTOK * 96 * 4);
    unsigned short* dtin_bf = (unsigned short*)alloc((size_t)NTOK * DT_RANK * 2);
    unsigned short* Wdt_bf = (unsigned short*)alloc((size_t)D_INNER * DT_RANK * 2);
    float* dtf = (float*)alloc((size_t)NTOK * D_INNER * 4);
    float* As = (float*)alloc((size_t)D_INNER * D_STATE * 4);
    unsigned short* y_bf = (unsigned short*)alloc((size_t)NTOK * D_INNER * 2);
    unsigned short* Wout_bf = (unsigned short*)alloc((size_t)D_MODEL * D_INNER * 2);
    unsigned short* out_bf = (unsigned short*)alloc((size_t)NTOK * D_MODEL * 2);
    float* Hinit = (float*)alloc((size_t)NB * NCHUNK * D_INNER * D_STATE * 4);  // 8.4 MB
    // head_w bf16 (65.5 MB) aliases xz (67 MB) — xz is dead after the scan
    unsigned short* Whead_bf = (unsigned short*)xz;
    // chunk-state buffers alias u_bf / Win_bf (each exactly 8,388,608 B, dead after GEMM #3)
    float* Pc = (float*)u_bf;       // NB*NCHUNK*D_INNER*D_STATE * 4 = 8,388,608 B
    float* Hc = (float*)Win_bf;     // same size

    dim3 blk(256);

    // 1. embedding gather
    embed_kernel<<<dim3(NTOK * D_MODEL / 4 / 256), blk, 0, stream>>>(tokens, emb, u_bf);
    // 2. in_proj weight -> bf16
    cvt_kernel<<<dim3(2 * D_INNER * D_MODEL / 4 / 256), blk, 0, stream>>>(in_proj_w, Win_bf, 2 * D_INNER * D_MODEL / 4);
    // 3. xz = u @ in_proj_w^T   [4096 x 4096], K=1024
    gemm_bf16<<<dim3(2 * D_INNER / 128, NTOK / 128), blk, 0, stream>>>(
        u_bf, Win_bf, xz, nullptr, nullptr, NTOK, 2 * D_INNER, D_MODEL, 0);
    // 4. conv + silu
    conv_silu_kernel<<<dim3(NTOK * D_INNER / 256), blk, 0, stream>>>(xz, conv_w, conv_b, xf, x_bf);
    // 5. x_proj weight -> bf16
    cvt_kernel<<<dim3((96 * D_INNER / 4 + 255) / 256), blk, 0, stream>>>(x_proj_w, Wxp_bf, 96 * D_INNER / 4);
    // 6. x_dbl = x @ x_proj_w^T  [4096 x 96], K=2048
    gemm_bf16<<<dim3(1, NTOK / 128), blk, 0, stream>>>(
        x_bf, Wxp_bf, xdbl, nullptr, nullptr, NTOK, 96, D_INNER, 0);
    // 7. extract dt-rank columns -> bf16
    dtin_kernel<<<dim3(NTOK * DT_RANK / 256), blk, 0, stream>>>(xdbl, dtin_bf);
    // 8. dt_proj weight -> bf16
    cvt_kernel<<<dim3((D_INNER * DT_RANK / 4 + 255) / 256), blk, 0, stream>>>(dt_proj_w, Wdt_bf, D_INNER * DT_RANK / 4);
    // 9. dt = softplus(dtin @ dt_proj_w^T + b)  [4096 x 2048], K=64
    gemm_bf16<<<dim3(D_INNER / 128, NTOK / 128), blk, 0, stream>>>(
        dtin_bf, Wdt_bf, dtf, nullptr, dt_proj_b, NTOK, D_INNER, DT_RANK, 1);
    // 10. As
    As_kernel<<<dim3((D_INNER * D_STATE + 255) / 256), blk, 0, stream>>>(A_log, As, D_INNER * D_STATE);
    // 11. chunked selective scan (3 kernels; fused +D*x, *silu(z), bf16 out)
    scan_part1<<<dim3(NB * NCHUNK * D_INNER * D_STATE / 256), blk, 0, stream>>>(
        dtf, xf, xdbl, As, Pc, Hc);
    scan_combine<<<dim3(NB * D_INNER * D_STATE / 256), blk, 0, stream>>>(Pc, Hc, Hinit);
    scan_part2<<<dim3(NB * NCHUNK * D_INNER * D_STATE / 256), blk, 0, stream>>>(
        dtf, xf, xdbl, xz, As, Dvec, Hinit, y_bf);
    // 12. out_proj weight -> bf16
    cvt_kernel<<<dim3(D_MODEL * D_INNER / 4 / 256), blk, 0, stream>>>(out_proj_w, Wout_bf, D_MODEL * D_INNER / 4);
    // 13. out = y @ out_proj_w^T  [4096 x 1024], K=2048, bf16 out
    gemm_bf16<<<dim3(D_MODEL / 128, NTOK / 128), blk, 0, stream>>>(
        y_bf, Wout_bf, nullptr, out_bf, nullptr, NTOK, D_MODEL, D_INNER, 3);
    // 14. head weight -> bf16 (into dead xz buffer)
    cvt_kernel<<<dim3(VOCAB * D_MODEL / 4 / 256), blk, 0, stream>>>(head_w, Whead_bf, VOCAB * D_MODEL / 4);
    // 15. logits = out @ head_w^T + head_b  [4096 x 32000], K=1024
    gemm_bf16<<<dim3(VOCAB / 128, NTOK / 128), blk, 0, stream>>>(
        out_bf, Whead_bf, logits, nullptr, head_b, NTOK, VOCAB, D_MODEL, 2);
}